// Round 3
// baseline (141.116 us; speedup 1.0000x reference)
//
#include <hip/hip_runtime.h>

#define DIM 8192
#define BATCH 256
#define BN 32
#define BK 64
#define NSTEP (DIM / BK)   // 128

typedef __attribute__((ext_vector_type(8))) short   short8;   // 8 bf16 (MFMA A/B frag)
typedef __attribute__((ext_vector_type(4))) float   f32x4;
typedef __attribute__((ext_vector_type(4))) unsigned short u16x4;

__device__ __forceinline__ unsigned short f2b(float f) {
    unsigned u = __builtin_bit_cast(unsigned, f);
    u = (u + 0x7FFFu + ((u >> 16) & 1u)) >> 16;
    return (unsigned short)u;
}

#define WAITV(N) asm volatile("s_waitcnt vmcnt(" #N ")" ::: "memory")
#define WAITL0   asm volatile("s_waitcnt lgkmcnt(0)" ::: "memory")
#define SCHEDB   __builtin_amdgcn_sched_barrier(0)
#define BARRIER  do { asm volatile("" ::: "memory"); __builtin_amdgcn_s_barrier(); asm volatile("" ::: "memory"); } while (0)

// ---- prepass: x f32 -> bf16 into workspace (4 MB) ----
__global__ __launch_bounds__(512) void cvt_x_kernel(const float* __restrict__ x,
                                                    unsigned short* __restrict__ xb) {
    int i = blockIdx.x * 512 + threadIdx.x;
    f32x4 v = reinterpret_cast<const f32x4*>(x)[i];
    u16x4 o;
    o[0] = f2b(v[0]); o[1] = f2b(v[1]); o[2] = f2b(v[2]); o[3] = f2b(v[3]);
    reinterpret_cast<u16x4*>(xb)[i] = o;
}

// ---- GEMM: out[b,i] = sum_j U[i,j] * x[b,j] ----
// 256 blocks x 512 threads. Block = 32 output cols x full batch; U read exactly once.
// Distance-4 register pipeline for BOTH U and A; one WAITV(15) + one barrier per step.
// LDS holds the B tile in MFMA-frag-linear order: frag fb read at byte fb*1024 + lane*16
// (conflict-free ds_read_b128). fb = (row>>4) + 2*(k>>5).
__global__ __launch_bounds__(512) void gemm_kernel(const unsigned short* __restrict__ xb,
                                                   const float* __restrict__ U,
                                                   float* __restrict__ out) {
    __shared__ unsigned short Blds[2 * 2048];   // 2 bufs x 4KB, frag-linear

    const int tid  = threadIdx.x;
    const int lane = tid & 63;
    const int w    = tid >> 6;
    const int n0   = blockIdx.x * BN;

    // U staging map: thread -> (row srow of 32, float4-quad sq of 16): 16B/thread/step
    const int srow = tid >> 4;
    const int sq   = tid & 15;
    const f32x4* Ub = reinterpret_cast<const f32x4*>(U + (long)(n0 + srow) * DIM + 4 * sq);
    // step t -> Ub[t*16]

    // LDS write slot (ushort index, sans buffer): element (row=srow, k0=4sq..+3)
    //   fb=(srow>>4)+2*(sq>>3); lane-slot=(srow&15)+((sq>>1)&3)*16; halfword j0=(4sq)&7
    const int wOff = ((srow >> 4) + 2 * (sq >> 3)) * 512
                   + ((srow & 15) + ((sq >> 1) & 3) * 16) * 8 + (sq & 1) * 4;
    // frag read base (ushort index): fb*512 + lane*8
    const int rOff = lane * 8;

    // A map: lane l -> batch row = 32w + (l&15) (+16), k = (l>>4)*8 (+32)
    const unsigned short* a0 = xb + (32 * w + (lane & 15)) * DIM + ((lane >> 4) * 8);
    const unsigned short* a1 = a0 + 16 * DIM;

    f32x4 acc00 = {0.f, 0.f, 0.f, 0.f};
    f32x4 acc01 = acc00, acc10 = acc00, acc11 = acc00;

    f32x4  Uq[4];        // U(n) in slot n&3
    short8 Aq[4][4];     // A(n) set in slot n&3: [0]=rows0-15 k0-31, [1]=rows0-15 k32-63,
                         //                      [2]=rows16-31 k0-31, [3]=rows16-31 k32-63

    // ---- prologue: issue order [U(0),A(0)x4, U(1),A(1)x4, U(2),A(2)x4, U(3),A(3)x4]
#pragma unroll
    for (int i = 0; i < 4; ++i) {
        Uq[i]    = Ub[i * 16];
        Aq[i][0] = *(const short8*)(a0 + i * BK);
        Aq[i][1] = *(const short8*)(a0 + i * BK + 32);
        Aq[i][2] = *(const short8*)(a1 + i * BK);
        Aq[i][3] = *(const short8*)(a1 + i * BK + 32);
    }
    WAITV(15); SCHEDB;                         // U(0) (and A(0)) arrived
    {
        u16x4 o; o[0] = f2b(Uq[0][0]); o[1] = f2b(Uq[0][1]);
        o[2] = f2b(Uq[0][2]); o[3] = f2b(Uq[0][3]);
        *reinterpret_cast<u16x4*>(&Blds[wOff]) = o;          // buf0
    }
    WAITL0;
    BARRIER;

    // Steady state: 15 loads in flight entering each step; step S(t):
    //  ds_read B(t) | issue U(t+4) | WAITV(15) [A(t),U(t+1) done] | cvt+write U(t+1)->buf^1
    //  | lgkm0 | barrier | MFMA(t) | issue A(t+4) into slot t&3
#define STEP(T, SI, SW, PB)                                                          \
    do {                                                                             \
        short8 b00 = *(const short8*)&Blds[(PB) * 2048 + 0 * 512 + rOff];            \
        short8 b10 = *(const short8*)&Blds[(PB) * 2048 + 1 * 512 + rOff];            \
        short8 b01 = *(const short8*)&Blds[(PB) * 2048 + 2 * 512 + rOff];            \
        short8 b11 = *(const short8*)&Blds[(PB) * 2048 + 3 * 512 + rOff];            \
        { int tp = ((T) + 4 < NSTEP) ? (T) + 4 : NSTEP - 1; Uq[SI] = Ub[tp * 16]; }  \
        WAITV(15); SCHEDB;                                                           \
        {                                                                            \
            u16x4 o; o[0] = f2b(Uq[SW][0]); o[1] = f2b(Uq[SW][1]);                   \
            o[2] = f2b(Uq[SW][2]); o[3] = f2b(Uq[SW][3]);                            \
            *reinterpret_cast<u16x4*>(&Blds[((PB) ^ 1) * 2048 + wOff]) = o;          \
        }                                                                            \
        WAITL0;                                                                      \
        BARRIER;                                                                     \
        __builtin_amdgcn_s_setprio(1);                                               \
        acc00 = __builtin_amdgcn_mfma_f32_16x16x32_bf16(Aq[SI][0], b00, acc00, 0, 0, 0); \
        acc01 = __builtin_amdgcn_mfma_f32_16x16x32_bf16(Aq[SI][0], b10, acc01, 0, 0, 0); \
        acc10 = __builtin_amdgcn_mfma_f32_16x16x32_bf16(Aq[SI][2], b00, acc10, 0, 0, 0); \
        acc11 = __builtin_amdgcn_mfma_f32_16x16x32_bf16(Aq[SI][2], b10, acc11, 0, 0, 0); \
        acc00 = __builtin_amdgcn_mfma_f32_16x16x32_bf16(Aq[SI][1], b01, acc00, 0, 0, 0); \
        acc01 = __builtin_amdgcn_mfma_f32_16x16x32_bf16(Aq[SI][1], b11, acc01, 0, 0, 0); \
        acc10 = __builtin_amdgcn_mfma_f32_16x16x32_bf16(Aq[SI][3], b01, acc10, 0, 0, 0); \
        acc11 = __builtin_amdgcn_mfma_f32_16x16x32_bf16(Aq[SI][3], b11, acc11, 0, 0, 0); \
        __builtin_amdgcn_s_setprio(0);                                               \
        { int ta = ((T) + 4 < NSTEP) ? (T) + 4 : NSTEP - 1;                          \
          Aq[SI][0] = *(const short8*)(a0 + ta * BK);                                \
          Aq[SI][1] = *(const short8*)(a0 + ta * BK + 32);                           \
          Aq[SI][2] = *(const short8*)(a1 + ta * BK);                                \
          Aq[SI][3] = *(const short8*)(a1 + ta * BK + 32); }                         \
    } while (0)

    for (int t = 0; t < NSTEP; t += 4) {
        STEP(t + 0, 0, 1, 0);
        STEP(t + 1, 1, 2, 1);
        STEP(t + 2, 2, 3, 0);
        STEP(t + 3, 3, 0, 1);
    }
#undef STEP

    // ---- epilogue: D mapping row=(l>>4)*4+r, col=l&15 (verified)
    const int orow = 32 * w + (lane >> 4) * 4;
    const int ocol = n0 + (lane & 15);
    float* o = out + (long)orow * DIM + ocol;
#pragma unroll
    for (int r = 0; r < 4; ++r) {
        o[(long)r * DIM]             = acc00[r];
        o[(long)r * DIM + 16]        = acc01[r];
        o[(long)(r + 16) * DIM]      = acc10[r];
        o[(long)(r + 16) * DIM + 16] = acc11[r];
    }
}

extern "C" void kernel_launch(void* const* d_in, const int* in_sizes, int n_in,
                              void* d_out, int out_size, void* d_ws, size_t ws_size,
                              hipStream_t stream) {
    const float* x = (const float*)d_in[0];     // [256, 8192] f32
    const float* U = (const float*)d_in[1];     // [8192, 8192] f32
    float* outp = (float*)d_out;                // [256, 8192] f32
    unsigned short* xb = (unsigned short*)d_ws; // 4 MB bf16 copy of x

    cvt_x_kernel<<<(BATCH * DIM / 4) / 512, 512, 0, stream>>>(x, xb);
    gemm_kernel<<<DIM / BN, 512, 0, stream>>>(xb, U, outp);
}